// Round 11
// baseline (3248.553 us; speedup 1.0000x reference)
//
#include <hip/hip_runtime.h>
#include <hip/hip_bf16.h>

#define E_ 8
#define H_ 2048
#define D_ 4096
#define R_ 8
#define T_ 2048
#define TWO_D_ 8192
#define SCALE_ 2.0f

typedef __attribute__((ext_vector_type(8))) short short8;
typedef __attribute__((ext_vector_type(4))) float f32x4;

__device__ __forceinline__ unsigned short f2bf(float f) {
  union { float f; unsigned u; } c; c.f = f;
  unsigned u = c.u + 0x7fffu + ((c.u >> 16) & 1u);  // RNE
  return (unsigned short)(u >> 16);
}
__device__ __forceinline__ float bf2f(unsigned short s) {
  union { unsigned u; float f; } c; c.u = ((unsigned)s) << 16;
  return c.f;
}

// async 16B global -> LDS (linear dest: wave-uniform base + lane*16)
__device__ __forceinline__ void gl16(const void* g, void* l) {
  __builtin_amdgcn_global_load_lds(
      (const __attribute__((address_space(1))) void*)g,
      (__attribute__((address_space(3))) void*)l, 16, 0, 0);
}

// LDS byte offset inside a 32KB operand region laid out [qtr][half][32 rows][64 cols bf16]
__device__ __forceinline__ int lds_off(int rr, int ks, int lq) {
  return (((rr >> 5) & 3) << 13) | (((rr >> 7) & 1) << 12) | ((rr & 31) << 7) | (ks << 6) | (lq << 4);
}

// ---------------- fused pre-pass: low1 = x@Agu^T + x->bf16  ||  Wgu->bf16  ||  Wd->bf16
__global__ __launch_bounds__(256) void k_pre(const float* __restrict__ x,
                                             const float* __restrict__ Agu,
                                             float* __restrict__ low,
                                             unsigned short* __restrict__ xb,
                                             const float* __restrict__ Wgu,
                                             unsigned short* __restrict__ wgub,
                                             const float* __restrict__ Wd,
                                             unsigned short* __restrict__ wdb) {
  const int NB_LOW = E_ * T_ / 4;  // 4096
  if (blockIdx.x < NB_LOW) {
    int wave = (blockIdx.x * 256 + threadIdx.x) >> 6;
    int lane = threadIdx.x & 63;
    int e = wave >> 11;
    const float* Ae = Agu + (long)e * R_ * H_;
    float acc[R_] = {0.f,0.f,0.f,0.f,0.f,0.f,0.f,0.f};
    for (int it = 0; it < H_ / 256; ++it) {
      int i = it * 256 + lane * 4;
      const float* xp = x + (long)wave * H_;
      f32x4 v = *(const f32x4*)(xp + i);
      ushort4 u; u.x=f2bf(v[0]); u.y=f2bf(v[1]); u.z=f2bf(v[2]); u.w=f2bf(v[3]);
      *(ushort4*)(xb + (long)wave * H_ + i) = u;
      #pragma unroll
      for (int r = 0; r < R_; ++r) {
        f32x4 a = *(const f32x4*)(Ae + r * H_ + i);
        acc[r] += v[0]*a[0] + v[1]*a[1] + v[2]*a[2] + v[3]*a[3];
      }
    }
    #pragma unroll
    for (int r = 0; r < R_; ++r) {
      float v = acc[r];
      #pragma unroll
      for (int off = 32; off > 0; off >>= 1) v += __shfl_xor(v, off);
      acc[r] = v;
    }
    if (lane == 0) {
      #pragma unroll
      for (int r = 0; r < R_; ++r) low[(long)wave * R_ + r] = acc[r];
    }
  } else if (blockIdx.x < NB_LOW + 1024) {
    const long n = (long)E_ * TWO_D_ * H_;
    long i = ((long)(blockIdx.x - NB_LOW) * 256 + threadIdx.x) * 8;
    const long stride = (long)1024 * 256 * 8;
    for (; i < n; i += stride) {
      f32x4 a = *(const f32x4*)(Wgu + i);
      f32x4 b = *(const f32x4*)(Wgu + i + 4);
      ushort4 lo, hi;
      lo.x=f2bf(a[0]); lo.y=f2bf(a[1]); lo.z=f2bf(a[2]); lo.w=f2bf(a[3]);
      hi.x=f2bf(b[0]); hi.y=f2bf(b[1]); hi.z=f2bf(b[2]); hi.w=f2bf(b[3]);
      *(ushort4*)(wgub + i) = lo;
      *(ushort4*)(wgub + i + 4) = hi;
    }
  } else {
    const long n = (long)E_ * H_ * D_;
    long i = ((long)(blockIdx.x - NB_LOW - 1024) * 256 + threadIdx.x) * 8;
    const long stride = (long)1024 * 256 * 8;
    for (; i < n; i += stride) {
      f32x4 a = *(const f32x4*)(Wd + i);
      f32x4 b = *(const f32x4*)(Wd + i + 4);
      ushort4 lo, hi;
      lo.x=f2bf(a[0]); lo.y=f2bf(a[1]); lo.z=f2bf(a[2]); lo.w=f2bf(a[3]);
      hi.x=f2bf(b[0]); hi.y=f2bf(b[1]); hi.z=f2bf(b[2]); hi.w=f2bf(b[3]);
      *(ushort4*)(wdb + i) = lo;
      *(ushort4*)(wdb + i + 4) = hi;
    }
  }
}

// ---------------- rank-8 projection from bf16 h (low2)
__global__ __launch_bounds__(256) void k_low2(const unsigned short* __restrict__ Hb,
                                              const float* __restrict__ Ad,
                                              float* __restrict__ low) {
  int wave = (blockIdx.x * 256 + threadIdx.x) >> 6;
  int lane = threadIdx.x & 63;
  int e = wave >> 11;
  const float* Ae = Ad + (long)e * R_ * D_;
  float acc[R_] = {0.f,0.f,0.f,0.f,0.f,0.f,0.f,0.f};
  for (int it = 0; it < D_ / 256; ++it) {
    int i = it * 256 + lane * 4;
    ushort4 u = *(const ushort4*)(Hb + (long)wave * D_ + i);
    float xv[4] = {bf2f(u.x), bf2f(u.y), bf2f(u.z), bf2f(u.w)};
    #pragma unroll
    for (int r = 0; r < R_; ++r) {
      f32x4 a = *(const f32x4*)(Ae + r * D_ + i);
      acc[r] += xv[0]*a[0] + xv[1]*a[1] + xv[2]*a[2] + xv[3]*a[3];
    }
  }
  #pragma unroll
  for (int r = 0; r < R_; ++r) {
    float v = acc[r];
    #pragma unroll
    for (int off = 32; off > 0; off >>= 1) v += __shfl_xor(v, off);
    acc[r] = v;
  }
  if (lane == 0) {
    #pragma unroll
    for (int r = 0; r < R_; ++r) low[(long)wave * R_ + r] = acc[r];
  }
}

// ======================= GEMM1: 256x128(gate)+128(up), BK=64, pipelined-read 4-phase ======
// h = up*silu(gate); gate_up = x@Wgu^T + SCALE*low1@Bgu^T (LoRA folded as rank-8 MFMA step)
// Fragment ds_reads issued one phase ahead (double reg sets); staging distributed per-phase
// (round-8 schedule); compiler inserts precise counted lgkmcnt before each consuming MFMA.
__global__ __launch_bounds__(512, 2) void k_gemm1_8p(
    const unsigned short* __restrict__ Xb, const unsigned short* __restrict__ Wb,
    const float* __restrict__ Bgu, const float* __restrict__ low,
    unsigned short* __restrict__ Hout) {
  __shared__ __align__(16) char lds[131072];  // A: d*32768, B: 65536 + d*32768

  const int MT = T_ / 256, NT = D_ / 128;  // 8, 32
  int b = blockIdx.x;
  int cpx = (int)gridDim.x >> 3;
  int swz = (b & 7) * cpx + (b >> 3);     // bijective: grid % 8 == 0
  int e  = swz / (MT * NT);
  int r0 = swz % (MT * NT);
  int nt = r0 / MT, mt = r0 % MT;

  int tid = threadIdx.x, lane = tid & 63;
  int wid = tid >> 6, wm = wid >> 2, wn = wid & 3;
  int lrow = lane & 15, lq = lane >> 4;
  int X4 = (lrow & 7) << 4;
  const int NKT = H_ / 64;  // 32

  unsigned ro = (unsigned)tid * 16;
  unsigned so = ro ^ (((ro >> 7) & 7u) << 4);
  int sh = (so >> 12) & 1, sr = (so >> 7) & 31, sc = (so & 127) >> 1;
  const unsigned short* pA[4]; const unsigned short* pB[4];
  #pragma unroll
  for (int q = 0; q < 4; ++q) {
    long arow = (long)e * T_ + mt * 256 + sh * 128 + q * 32 + sr;
    pA[q] = Xb + arow * H_ + sc;
    long wrow = sh ? ((long)e * TWO_D_ + D_ + nt * 128 + q * 32 + sr)
                   : ((long)e * TWO_D_ +      nt * 128 + q * 32 + sr);
    pB[q] = Wb + wrow * (long)H_ + sc;
  }
  auto SA = [&](int d, int q) { gl16(pA[q], lds + d * 32768 + q * 8192 + ro); pA[q] += 64; };
  auto SB = [&](int d, int q) { gl16(pB[q], lds + 65536 + d * 32768 + q * 8192 + ro); pB[q] += 64; };

  f32x4 accg[2][8] = {}, accu[2][8] = {};  // [nj][mi]
  short8 af0[2][2], af1[2][2];             // A frag double sets
  short8 BGa[2][2], BUa[2][2], BGb[2][2], BUb[2][2];  // B frag double sets
  int rbA = wm * 128 + lrow;

#define G1_MFMA(q, AF, BGs, BUs)                                                     \
    __builtin_amdgcn_s_setprio(1);                                                   \
    _Pragma("unroll") for (int m2 = 0; m2 < 2; ++m2)                                 \
      _Pragma("unroll") for (int ks = 0; ks < 2; ++ks)                               \
        _Pragma("unroll") for (int nj = 0; nj < 2; ++nj) {                           \
          accg[nj][(q)*2+m2] = __builtin_amdgcn_mfma_f32_16x16x32_bf16(              \
              BGs[nj][ks], AF[m2][ks], accg[nj][(q)*2+m2], 0, 0, 0);                 \
          accu[nj][(q)*2+m2] = __builtin_amdgcn_mfma_f32_16x16x32_bf16(              \
              BUs[nj][ks], AF[m2][ks], accu[nj][(q)*2+m2], 0, 0, 0);                 \
        }                                                                            \
    __builtin_amdgcn_s_setprio(0);

#define G1_LDA_Q(AF, Ab, q)                                                          \
    _Pragma("unroll") for (int m2 = 0; m2 < 2; ++m2)                                 \
      _Pragma("unroll") for (int ks = 0; ks < 2; ++ks)                               \
        AF[m2][ks] = *(const short8*)((Ab) + (lds_off(rbA + ((q)*2+m2)*16, ks, lq) ^ X4));

#define G1_LDB(BGs, BUs, Bb)                                                         \
    _Pragma("unroll") for (int nj = 0; nj < 2; ++nj)                                 \
      _Pragma("unroll") for (int ks = 0; ks < 2; ++ks) {                             \
        int rg = wn * 32 + nj * 16 + lrow;                                           \
        BGs[nj][ks] = *(const short8*)((Bb) + (lds_off(rg, ks, lq) ^ X4));           \
        BUs[nj][ks] = *(const short8*)((Bb) + (lds_off(rg + 128, ks, lq) ^ X4));     \
      }

// One K-tile. Reads for quad p+1 issued at phase p; MFMA(p) consumes prior-phase reads.
// Staging placement identical to proven round-8 schedule.
#define G1_TILE(tt, BGc, BUc, BGn, BUn)                                              \
  {                                                                                  \
    int d = (tt) & 1;                                                                \
    const char* Ab  = lds + d * 32768;                                               \
    const char* AbN = lds + (d ^ 1) * 32768;                                         \
    const char* BbN = lds + 65536 + (d ^ 1) * 32768;                                 \
    /* phase 0 */                                                                    \
    if ((tt) + 1 < NKT) { SA(d ^ 1, 3); SB(d ^ 1, 3); }                              \
    G1_LDA_Q(af1, Ab, 1);                                                            \
    __builtin_amdgcn_sched_barrier(0);                                               \
    G1_MFMA(0, af0, BGc, BUc);                                                       \
    __builtin_amdgcn_s_barrier();                                                    \
    /* phase 1 */                                                                    \
    if ((tt) + 2 < NKT) { SA(d, 0); SB(d, 0); }                                      \
    G1_LDA_Q(af0, Ab, 2);                                                            \
    __builtin_amdgcn_sched_barrier(0);                                               \
    G1_MFMA(1, af1, BGc, BUc);                                                       \
    __builtin_amdgcn_s_barrier();                                                    \
    /* phase 2 */                                                                    \
    if ((tt) + 2 < NKT) { SA(d, 1); SB(d, 1); }                                      \
    G1_LDA_Q(af1, Ab, 3);                                                            \
    __builtin_amdgcn_sched_barrier(0);                                               \
    G1_MFMA(2, af0, BGc, BUc);                                                       \
    __builtin_amdgcn_s_barrier();                                                    \
    /* phase 3: finish tile staging, make next buffer valid, boundary reads */       \
    if ((tt) + 2 < NKT) {                                                            \
      SA(d, 2); SB(d, 2);                                                            \
      asm volatile("s_waitcnt vmcnt(6)" ::: "memory");                               \
    } else {                                                                         \
      asm volatile("s_waitcnt vmcnt(0)" ::: "memory");                               \
    }                                                                                \
    __builtin_amdgcn_s_barrier();                                                    \
    if ((tt) + 1 < NKT) { G1_LDB(BGn, BUn, BbN); G1_LDA_Q(af0, AbN, 0); }            \
    __builtin_amdgcn_sched_barrier(0);                                               \
    G1_MFMA(3, af1, BGc, BUc);                                                       \
    __builtin_amdgcn_s_barrier();                                                    \
  }

  // ---- prologue: stage tile0 (all) + tile1 (units 0-2); wait tile0; boundary reads
  SA(0,0); SB(0,0); SA(0,1); SB(0,1); SA(0,2); SB(0,2); SA(0,3); SB(0,3);
  SA(1,0); SB(1,0); SA(1,1); SB(1,1); SA(1,2); SB(1,2);
  asm volatile("s_waitcnt vmcnt(6)" ::: "memory");
  __builtin_amdgcn_s_barrier();
  G1_LDB(BGa, BUa, lds + 65536);
  G1_LDA_Q(af0, lds, 0);

  for (int t = 0; t < NKT; t += 2) {
    G1_TILE(t,     BGa, BUa, BGb, BUb);
    G1_TILE(t + 1, BGb, BUb, BGa, BUa);
  }

  // ---- epilogue: fold LoRA via one rank-8 (K=32 zero-padded) MFMA step
  __syncthreads();
  unsigned short* sLo2 = (unsigned short*)lds;            // [256][32] bf16: SCALE*low1
  unsigned short* sB2  = (unsigned short*)(lds + 16384);  // [256][32] bf16: Bgu rows (gate|up)
  {
    short8 z = {};
    if (tid < 256) {
      const float* lp = low + ((long)e * T_ + mt * 256 + tid) * R_;
      short8 v;
      #pragma unroll
      for (int r = 0; r < 8; ++r) ((unsigned short*)&v)[r] = f2bf(SCALE_ * lp[r]);
      *(short8*)(sLo2 + tid * 32) = v;
      *(short8*)(sLo2 + tid * 32 + 8) = z;
      *(short8*)(sLo2 + tid * 32 + 16) = z;
      *(short8*)(sLo2 + tid * 32 + 24) = z;
    } else {
      int r = tid - 256;
      long wrow = (r < 128) ? ((long)e * TWO_D_ + nt * 128 + r)
                            : ((long)e * TWO_D_ + D_ + nt * 128 + (r - 128));
      const float* bp = Bgu + wrow * R_;
      short8 v;
      #pragma unroll
      for (int k = 0; k < 8; ++k) ((unsigned short*)&v)[k] = f2bf(bp[k]);
      *(short8*)(sB2 + r * 32) = v;
      *(short8*)(sB2 + r * 32 + 8) = z;
      *(short8*)(sB2 + r * 32 + 16) = z;
      *(short8*)(sB2 + r * 32 + 24) = z;
    }
  }
  __syncthreads();
  {
    #pragma unroll
    for (int mi = 0; mi < 8; ++mi) {
      short8 alo = *(const short8*)(sLo2 + (rbA + mi * 16) * 32 + lq * 8);
      #pragma unroll
      for (int nj = 0; nj < 2; ++nj) {
        int rg = wn * 32 + nj * 16 + lrow;
        short8 bg2 = *(const short8*)(sB2 + rg * 32 + lq * 8);
        short8 bu2 = *(const short8*)(sB2 + (rg + 128) * 32 + lq * 8);
        accg[nj][mi] = __builtin_amdgcn_mfma_f32_16x16x32_bf16(bg2, alo, accg[nj][mi], 0, 0, 0);
        accu[nj][mi] = __builtin_amdgcn_mfma_f32_16x16x32_bf16(bu2, alo, accu[nj][mi], 0, 0, 0);
      }
    }
  }
  // silu + pack -> sT [256][136], then coalesced store
  unsigned short* sT = (unsigned short*)(lds + 32768);
  #pragma unroll
  for (int mi = 0; mi < 8; ++mi) {
    int tl = rbA + mi * 16;
    #pragma unroll
    for (int nj = 0; nj < 2; ++nj) {
      int cb = wn * 32 + nj * 16 + lq * 4;
      ushort4 o;
      #pragma unroll
      for (int j = 0; j < 4; ++j) {
        float gate = accg[nj][mi][j];
        float up   = accu[nj][mi][j];
        float hh = up * (gate / (1.f + __expf(-gate)));
        (&o.x)[j] = f2bf(hh);
      }
      *(ushort4*)(sT + tl * 136 + cb) = o;
    }
  }
  __syncthreads();
  {
    long base = ((long)e * T_ + mt * 256) * D_ + nt * 128;
    int rr2 = tid >> 4, cc2 = (tid & 15) * 8;
    #pragma unroll
    for (int p = 0; p < 8; ++p) {
      int r = p * 32 + rr2;
      short8 v = *(const short8*)(sT + r * 136 + cc2);
      *(short8*)(Hout + base + (long)r * D_ + cc2) = v;
    }
  }
}

// ======================= GEMM2: 256x256, BK=64, pipelined-read 4-phase =======================
// out = h@Wd^T + SCALE*low2@Bd^T (fp32 out; LoRA folded as rank-8 MFMA step)
__global__ __launch_bounds__(512, 2) void k_gemm2_8p(
    const unsigned short* __restrict__ Hin, const unsigned short* __restrict__ Wdb,
    const float* __restrict__ Bd, const float* __restrict__ low,
    float* __restrict__ Out) {
  __shared__ __align__(16) char lds[131072];

  const int MT = T_ / 256, NT = H_ / 256;  // 8, 8
  int b = blockIdx.x;
  int cpx = (int)gridDim.x >> 3;
  int swz = (b & 7) * cpx + (b >> 3);
  int e  = swz / (MT * NT);
  int r0 = swz % (MT * NT);
  int nt = r0 / MT, mt = r0 % MT;

  int tid = threadIdx.x, lane = tid & 63;
  int wid = tid >> 6, wm = wid >> 2, wn = wid & 3;
  int lrow = lane & 15, lq = lane >> 4;
  int X4 = (lrow & 7) << 4;
  const int NKT = D_ / 64;  // 64

  unsigned ro = (unsigned)tid * 16;
  unsigned so = ro ^ (((ro >> 7) & 7u) << 4);
  int sh = (so >> 12) & 1, sr = (so >> 7) & 31, sc = (so & 127) >> 1;
  const unsigned short* pA[4]; const unsigned short* pB[4];
  #pragma unroll
  for (int q = 0; q < 4; ++q) {
    long arow = (long)e * T_ + mt * 256 + sh * 128 + q * 32 + sr;
    pA[q] = Hin + arow * D_ + sc;
    long wrow = (long)e * H_ + nt * 256 + sh * 128 + q * 32 + sr;
    pB[q] = Wdb + wrow * (long)D_ + sc;
  }
  auto SA = [&](int d, int q) { gl16(pA[q], lds + d * 32768 + q * 8192 + ro); pA[q] += 64; };
  auto SB = [&](int d, int q) { gl16(pB[q], lds + 65536 + d * 32768 + q * 8192 + ro); pB[q] += 64; };

  f32x4 acc[8][4] = {};  // [mi][ni]
  short8 af0[2][2], af1[2][2];
  short8 BFa[4][2], BFb[4][2];
  int rbA = wm * 128 + lrow;

#define G2_MFMA(q, AF, BFs)                                                          \
    __builtin_amdgcn_s_setprio(1);                                                   \
    _Pragma("unroll") for (int m2 = 0; m2 < 2; ++m2)                                 \
      _Pragma("unroll") for (int ks = 0; ks < 2; ++ks)                               \
        _Pragma("unroll") for (int ni = 0; ni < 4; ++ni)                             \
          acc[(q)*2+m2][ni] = __builtin_amdgcn_mfma_f32_16x16x32_bf16(               \
              AF[m2][ks], BFs[ni][ks], acc[(q)*2+m2][ni], 0, 0, 0);                  \
    __builtin_amdgcn_s_setprio(0);

#define G2_LDA_Q(AF, Ab, q)                                                          \
    _Pragma("unroll") for (int m2 = 0; m2 < 2; ++m2)                                 \
      _Pragma("unroll") for (int ks = 0; ks < 2; ++ks)                               \
        AF[m2][ks] = *(const short8*)((Ab) + (lds_off(rbA + ((q)*2+m2)*16, ks, lq) ^ X4));

#define G2_LDB(BFs, Bb)                                                              \
    _Pragma("unroll") for (int ni = 0; ni < 4; ++ni)                                 \
      _Pragma("unroll") for (int ks = 0; ks < 2; ++ks)                               \
        BFs[ni][ks] = *(const short8*)((Bb) + (lds_off(wn * 64 + ni * 16 + lrow, ks, lq) ^ X4));

#define G2_TILE(tt, BFc, BFn)                                                        \
  {                                                                                  \
    int d = (tt) & 1;                                                                \
    const char* Ab  = lds + d * 32768;                                               \
    const char* AbN = lds + (d ^ 1) * 32768;                                         \
    const char* BbN = lds + 65536 + (d ^ 1) * 32768;                                 \
    /* phase 0 */                                                                    \
    if ((tt) + 1 < NKT) { SA(d ^ 1, 3); SB(d ^ 1, 3); }                              \
    G2_LDA_Q(af1, Ab, 1);                                                            \
    __builtin_amdgcn_sched_barrier(0);                                               \
    G2_MFMA(0, af0, BFc);                                                            \
    __builtin_amdgcn_s_barrier();                                                    \
    /* phase 1 */                                                                    \
    if ((tt) + 2 < NKT) { SA(d, 0); SB(d, 0); }                                      \
    G2_LDA_Q(af0, Ab, 2);                                                            \
    __builtin_amdgcn_sched_barrier(0);                                               \
    G2_MFMA(1, af1, BFc);                                                            \
    __builtin_amdgcn_s_barrier();                                                    \
    /* phase 2 */                                                                    \
    if ((tt) + 2 < NKT) { SA(d, 1); SB(d, 1); }                                      \
    G2_LDA_Q(af1, Ab, 3);                                                            \
    __builtin_amdgcn_sched_barrier(0);                                               \
    G2_MFMA(2, af0, BFc);                                                            \
    __builtin_amdgcn_s_barrier();                                                    \
    /* phase 3 */                                                                    \
    if ((tt) + 2 < NKT) {                                                            \
      SA(d, 2); SB(d, 2);                                                            \
      asm volatile("s_waitcnt vmcnt(6)" ::: "memory");                               \
    } else {                                                                         \
      asm volatile("s_waitcnt vmcnt(0)" ::: "memory");                               \
    }                                                                                \
    __builtin_amdgcn_s_barrier();                                                    \
    if ((tt) + 1 < NKT) { G2_LDB(BFn, BbN); G2_LDA_Q(af0, AbN, 0); }                 \
    __builtin_amdgcn_sched_barrier(0);                                               \
    G2_MFMA(3, af1, BFc);                                                            \
    __builtin_amdgcn_s_barrier();                                                    \
  }

  SA(0,0); SB(0,0); SA(0,1); SB(0,1); SA(0,2); SB(0,2); SA(0,3); SB(0,3);
  SA(1,0); SB(1,0); SA(1,1); SB(1,1); SA(1,2); SB(1,2);
  asm volatile("s_waitcnt vmcnt(6)" ::: "memory");
  __builtin_amdgcn_s_barrier();
  G2_LDB(BFa, lds + 65536);
  G2_LDA_Q(af0, lds, 0);

  for (int t = 0; t < NKT; t += 2) {
    G2_TILE(t,     BFa, BFb);
    G2_TILE(t + 1, BFb, BFa);
  }

  // ---- epilogue: LoRA via rank-8 MFMA, direct (row-major) stores
  __syncthreads();
  unsigned short* sLo2 = (unsigned short*)lds;            // [256][32] SCALE*low2
  unsigned short* sB2  = (unsigned short*)(lds + 16384);  // [256][32] Bd rows
  {
    short8 z = {};
    if (tid < 256) {
      const float* lp = low + ((long)e * T_ + mt * 256 + tid) * R_;
      short8 v;
      #pragma unroll
      for (int r = 0; r < 8; ++r) ((unsigned short*)&v)[r] = f2bf(SCALE_ * lp[r]);
      *(short8*)(sLo2 + tid * 32) = v;
      *(short8*)(sLo2 + tid * 32 + 8) = z;
      *(short8*)(sLo2 + tid * 32 + 16) = z;
      *(short8*)(sLo2 + tid * 32 + 24) = z;
    } else {
      int r = tid - 256;
      const float* bp = Bd + ((long)e * H_ + nt * 256 + r) * R_;
      short8 v;
      #pragma unroll
      for (int k = 0; k < 8; ++k) ((unsigned short*)&v)[k] = f2bf(bp[k]);
      *(short8*)(sB2 + r * 32) = v;
      *(short8*)(sB2 + r * 32 + 8) = z;
      *(short8*)(sB2 + r * 32 + 16) = z;
      *(short8*)(sB2 + r * 32 + 24) = z;
    }
  }
  __syncthreads();
  #pragma unroll
  for (int mi = 0; mi < 8; ++mi) {
    short8 alo = *(const short8*)(sLo2 + (rbA + mi * 16) * 32 + lq * 8);
    #pragma unroll
    for (int ni = 0; ni < 4; ++ni) {
      short8 bd2 = *(const short8*)(sB2 + (wn * 64 + ni * 16 + lrow) * 32 + lq * 8);
      acc[mi][ni] = __builtin_amdgcn_mfma_f32_16x16x32_bf16(alo, bd2, acc[mi][ni], 0, 0, 0);
    }
  }
  {
    long rowbase = (long)e * T_ + mt * 256 + wm * 128;
    int colbase = nt * 256 + wn * 64;
    #pragma unroll
    for (int mi = 0; mi < 8; ++mi)
      #pragma unroll
      for (int j = 0; j < 4; ++j) {
        long row = rowbase + mi * 16 + lq * 4 + j;
        #pragma unroll
        for (int ni = 0; ni < 4; ++ni)
          Out[row * H_ + colbase + ni * 16 + lrow] = acc[mi][ni][j];
      }
  }
}

extern "C" void kernel_launch(void* const* d_in, const int* in_sizes, int n_in,
                              void* d_out, int out_size, void* d_ws, size_t ws_size,
                              hipStream_t stream) {
  const float* x   = (const float*)d_in[0];
  const float* Wgu = (const float*)d_in[1];
  const float* Agu = (const float*)d_in[2];
  const float* Bgu = (const float*)d_in[3];
  const float* Wd  = (const float*)d_in[4];
  const float* Ad  = (const float*)d_in[5];
  const float* Bd  = (const float*)d_in[6];
  float* out = (float*)d_out;

  char* ws = (char*)d_ws;
  const size_t SZ_H   = (size_t)E_ * T_ * D_ * 2;        // 128 MiB bf16 h
  const size_t SZ_LOW = (size_t)E_ * T_ * R_ * 4;        // 512 KiB
  const size_t SZ_XB  = (size_t)E_ * T_ * H_ * 2;        // 64 MiB
  const size_t SZ_WGU = (size_t)E_ * TWO_D_ * H_ * 2;    // 256 MiB

  unsigned short* hbuf = (unsigned short*)ws;
  float* low1 = (float*)(ws + SZ_H);
  float* low2 = (float*)(ws + SZ_H + SZ_LOW);
  unsigned short* xb   = (unsigned short*)(ws + SZ_H + 2 * SZ_LOW);
  unsigned short* wgub = (unsigned short*)(ws + SZ_H + 2 * SZ_LOW + SZ_XB);
  unsigned short* wdb  = (unsigned short*)(ws + SZ_H + 2 * SZ_LOW + SZ_XB + SZ_WGU);

  // low1 + x->bf16 (blocks 0..4095) || Wgu->bf16 (1024 blocks) || Wd->bf16 (1024 blocks)
  hipLaunchKernelGGL(k_pre, dim3(E_ * T_ / 4 + 2048), dim3(256), 0, stream,
                     x, Agu, low1, xb, Wgu, wgub, Wd, wdb);
  hipLaunchKernelGGL(k_gemm1_8p, dim3(E_ * (T_ / 256) * (D_ / 128)), dim3(512), 0, stream,
                     xb, wgub, Bgu, low1, hbuf);
  hipLaunchKernelGGL(k_low2, dim3(E_ * T_ / 4), dim3(256), 0, stream, hbuf, Ad, low2);
  hipLaunchKernelGGL(k_gemm2_8p, dim3(E_ * (T_ / 256) * (H_ / 256)), dim3(512), 0, stream,
                     hbuf, wdb, Bd, low2, out);
}

// Round 12
// 1118.459 us; speedup vs baseline: 2.9045x; 2.9045x over previous
//
#include <hip/hip_runtime.h>
#include <hip/hip_bf16.h>

#define E_ 8
#define H_ 2048
#define D_ 4096
#define R_ 8
#define T_ 2048
#define TWO_D_ 8192
#define SCALE_ 2.0f

typedef __attribute__((ext_vector_type(8))) short short8;
typedef __attribute__((ext_vector_type(4))) float f32x4;

__device__ __forceinline__ unsigned short f2bf(float f) {
  union { float f; unsigned u; } c; c.f = f;
  unsigned u = c.u + 0x7fffu + ((c.u >> 16) & 1u);  // RNE
  return (unsigned short)(u >> 16);
}
__device__ __forceinline__ float bf2f(unsigned short s) {
  union { unsigned u; float f; } c; c.u = ((unsigned)s) << 16;
  return c.f;
}

// async 16B global -> LDS (linear dest: wave-uniform base + lane*16)
__device__ __forceinline__ void gl16(const void* g, void* l) {
  __builtin_amdgcn_global_load_lds(
      (const __attribute__((address_space(1))) void*)g,
      (__attribute__((address_space(3))) void*)l, 16, 0, 0);
}

// LDS byte offset inside a 32KB operand region laid out [qtr][half][32 rows][64 cols bf16]
__device__ __forceinline__ int lds_off(int rr, int ks, int lq) {
  return (((rr >> 5) & 3) << 13) | (((rr >> 7) & 1) << 12) | ((rr & 31) << 7) | (ks << 6) | (lq << 4);
}

// ---------------- pre-pass: low1 = x@Agu^T + x->bf16  ||  Wgu->bf16
__global__ __launch_bounds__(256) void k_pre(const float* __restrict__ x,
                                             const float* __restrict__ Agu,
                                             float* __restrict__ low,
                                             unsigned short* __restrict__ xb,
                                             const float* __restrict__ Wgu,
                                             unsigned short* __restrict__ wgub) {
  const int NB_LOW = E_ * T_ / 4;  // 4096
  if (blockIdx.x < NB_LOW) {
    int wave = (blockIdx.x * 256 + threadIdx.x) >> 6;
    int lane = threadIdx.x & 63;
    int e = wave >> 11;
    const float* Ae = Agu + (long)e * R_ * H_;
    float acc[R_] = {0.f,0.f,0.f,0.f,0.f,0.f,0.f,0.f};
    for (int it = 0; it < H_ / 256; ++it) {
      int i = it * 256 + lane * 4;
      const float* xp = x + (long)wave * H_;
      f32x4 v = *(const f32x4*)(xp + i);
      ushort4 u; u.x=f2bf(v[0]); u.y=f2bf(v[1]); u.z=f2bf(v[2]); u.w=f2bf(v[3]);
      *(ushort4*)(xb + (long)wave * H_ + i) = u;
      #pragma unroll
      for (int r = 0; r < R_; ++r) {
        f32x4 a = *(const f32x4*)(Ae + r * H_ + i);
        acc[r] += v[0]*a[0] + v[1]*a[1] + v[2]*a[2] + v[3]*a[3];
      }
    }
    #pragma unroll
    for (int r = 0; r < R_; ++r) {
      float v = acc[r];
      #pragma unroll
      for (int off = 32; off > 0; off >>= 1) v += __shfl_xor(v, off);
      acc[r] = v;
    }
    if (lane == 0) {
      #pragma unroll
      for (int r = 0; r < R_; ++r) low[(long)wave * R_ + r] = acc[r];
    }
  } else {
    const long n = (long)E_ * TWO_D_ * H_;
    long i = ((long)(blockIdx.x - NB_LOW) * 256 + threadIdx.x) * 8;
    const long stride = (long)1024 * 256 * 8;
    for (; i < n; i += stride) {
      f32x4 a = *(const f32x4*)(Wgu + i);
      f32x4 b = *(const f32x4*)(Wgu + i + 4);
      ushort4 lo, hi;
      lo.x=f2bf(a[0]); lo.y=f2bf(a[1]); lo.z=f2bf(a[2]); lo.w=f2bf(a[3]);
      hi.x=f2bf(b[0]); hi.y=f2bf(b[1]); hi.z=f2bf(b[2]); hi.w=f2bf(b[3]);
      *(ushort4*)(wgub + i) = lo;
      *(ushort4*)(wgub + i + 4) = hi;
    }
  }
}

// ---------------- low2 = h@Ad^T  ||  Wd->bf16 (runs between gemm1 and gemm2)
__global__ __launch_bounds__(256) void k_low2(const unsigned short* __restrict__ Hb,
                                              const float* __restrict__ Ad,
                                              float* __restrict__ low,
                                              const float* __restrict__ Wd,
                                              unsigned short* __restrict__ wdb) {
  const int NB_LOW = E_ * T_ / 4;  // 4096
  if (blockIdx.x < NB_LOW) {
    int wave = (blockIdx.x * 256 + threadIdx.x) >> 6;
    int lane = threadIdx.x & 63;
    int e = wave >> 11;
    const float* Ae = Ad + (long)e * R_ * D_;
    float acc[R_] = {0.f,0.f,0.f,0.f,0.f,0.f,0.f,0.f};
    for (int it = 0; it < D_ / 256; ++it) {
      int i = it * 256 + lane * 4;
      ushort4 u = *(const ushort4*)(Hb + (long)wave * D_ + i);
      float xv[4] = {bf2f(u.x), bf2f(u.y), bf2f(u.z), bf2f(u.w)};
      #pragma unroll
      for (int r = 0; r < R_; ++r) {
        f32x4 a = *(const f32x4*)(Ae + r * D_ + i);
        acc[r] += xv[0]*a[0] + xv[1]*a[1] + xv[2]*a[2] + xv[3]*a[3];
      }
    }
    #pragma unroll
    for (int r = 0; r < R_; ++r) {
      float v = acc[r];
      #pragma unroll
      for (int off = 32; off > 0; off >>= 1) v += __shfl_xor(v, off);
      acc[r] = v;
    }
    if (lane == 0) {
      #pragma unroll
      for (int r = 0; r < R_; ++r) low[(long)wave * R_ + r] = acc[r];
    }
  } else {
    const long n = (long)E_ * H_ * D_;
    long i = ((long)(blockIdx.x - NB_LOW) * 256 + threadIdx.x) * 8;
    const long stride = (long)1024 * 256 * 8;
    for (; i < n; i += stride) {
      f32x4 a = *(const f32x4*)(Wd + i);
      f32x4 b = *(const f32x4*)(Wd + i + 4);
      ushort4 lo, hi;
      lo.x=f2bf(a[0]); lo.y=f2bf(a[1]); lo.z=f2bf(a[2]); lo.w=f2bf(a[3]);
      hi.x=f2bf(b[0]); hi.y=f2bf(b[1]); hi.z=f2bf(b[2]); hi.w=f2bf(b[3]);
      *(ushort4*)(wdb + i) = lo;
      *(ushort4*)(wdb + i + 4) = hi;
    }
  }
}

// ======================= GEMM1: 256x128(gate)+128(up), BK=64, 8-phase =======================
// h = up*silu(gate); gate_up = x@Wgu^T + SCALE*low1@Bgu^T (LoRA folded as rank-8 MFMA step)
__global__ __launch_bounds__(512, 2) void k_gemm1_8p(
    const unsigned short* __restrict__ Xb, const unsigned short* __restrict__ Wb,
    const float* __restrict__ Bgu, const float* __restrict__ low,
    unsigned short* __restrict__ Hout) {
  __shared__ __align__(16) char lds[131072];  // A: d*32768, B: 65536 + d*32768

  const int MT = T_ / 256, NT = D_ / 128;  // 8, 32
  int b = blockIdx.x;
  int cpx = (int)gridDim.x >> 3;
  int swz = (b & 7) * cpx + (b >> 3);     // bijective: grid % 8 == 0
  int e  = swz / (MT * NT);
  int r0 = swz % (MT * NT);
  int nt = r0 / MT, mt = r0 % MT;

  int tid = threadIdx.x, lane = tid & 63;
  int wid = tid >> 6, wm = wid >> 2, wn = wid & 3;
  int lrow = lane & 15, lq = lane >> 4;
  int X4 = (lrow & 7) << 4;
  const int NKT = H_ / 64;  // 32

  unsigned ro = (unsigned)tid * 16;
  unsigned so = ro ^ (((ro >> 7) & 7u) << 4);
  int sh = (so >> 12) & 1, sr = (so >> 7) & 31, sc = (so & 127) >> 1;
  const unsigned short* pA[4]; const unsigned short* pB[4];
  #pragma unroll
  for (int q = 0; q < 4; ++q) {
    long arow = (long)e * T_ + mt * 256 + sh * 128 + q * 32 + sr;
    pA[q] = Xb + arow * H_ + sc;
    long wrow = sh ? ((long)e * TWO_D_ + D_ + nt * 128 + q * 32 + sr)
                   : ((long)e * TWO_D_ +      nt * 128 + q * 32 + sr);
    pB[q] = Wb + wrow * (long)H_ + sc;
  }
  auto SA = [&](int d, int q) { gl16(pA[q], lds + d * 32768 + q * 8192 + ro); pA[q] += 64; };
  auto SB = [&](int d, int q) { gl16(pB[q], lds + 65536 + d * 32768 + q * 8192 + ro); pB[q] += 64; };

  f32x4 accg[2][8] = {}, accu[2][8] = {};  // [nj][mi]
  short8 BG[2][2], BU[2][2], af[2][2];

  SA(0,0); SB(0,0); SA(0,1); SB(0,1); SA(0,2); SB(0,2); SA(0,3); SB(0,3);
  SA(1,0); SB(1,0); SA(1,1); SB(1,1); SA(1,2); SB(1,2);
  asm volatile("s_waitcnt vmcnt(6)" ::: "memory");
  __builtin_amdgcn_s_barrier();

  int rbA = wm * 128 + lrow;
  for (int t = 0; t < NKT; ++t) {
    int d = t & 1;
    const char* Ab = lds + d * 32768;
    const char* Bb = lds + 65536 + d * 32768;

#define G1_MFMA(q)                                                                   \
    __builtin_amdgcn_s_setprio(1);                                                   \
    _Pragma("unroll") for (int m2 = 0; m2 < 2; ++m2)                                 \
      _Pragma("unroll") for (int ks = 0; ks < 2; ++ks)                               \
        _Pragma("unroll") for (int nj = 0; nj < 2; ++nj) {                           \
          accg[nj][(q)*2+m2] = __builtin_amdgcn_mfma_f32_16x16x32_bf16(              \
              BG[nj][ks], af[m2][ks], accg[nj][(q)*2+m2], 0, 0, 0);                  \
          accu[nj][(q)*2+m2] = __builtin_amdgcn_mfma_f32_16x16x32_bf16(              \
              BU[nj][ks], af[m2][ks], accu[nj][(q)*2+m2], 0, 0, 0);                  \
        }                                                                            \
    __builtin_amdgcn_s_setprio(0);

#define G1_LDA(q)                                                                    \
    _Pragma("unroll") for (int m2 = 0; m2 < 2; ++m2)                                 \
      _Pragma("unroll") for (int ks = 0; ks < 2; ++ks)                               \
        af[m2][ks] = *(const short8*)(Ab + (lds_off(rbA + ((q)*2+m2)*16, ks, lq) ^ X4));

#define G1_SYNC()                                                                    \
    __builtin_amdgcn_s_barrier();                                                    \
    asm volatile("s_waitcnt lgkmcnt(0)" ::: "memory");                               \
    __builtin_amdgcn_sched_barrier(0);

    // phase 0: B-frags + A-quad0; stage tile t+1 last units
    #pragma unroll
    for (int nj = 0; nj < 2; ++nj)
      #pragma unroll
      for (int ks = 0; ks < 2; ++ks) {
        int rg = wn * 32 + nj * 16 + lrow;
        BG[nj][ks] = *(const short8*)(Bb + (lds_off(rg, ks, lq) ^ X4));
        BU[nj][ks] = *(const short8*)(Bb + (lds_off(rg + 128, ks, lq) ^ X4));
      }
    G1_LDA(0);
    if (t + 1 < NKT) { SA(d ^ 1, 3); SB(d ^ 1, 3); }
    G1_SYNC();
    G1_MFMA(0);
    __builtin_amdgcn_s_barrier();
    // phase 1
    G1_LDA(1);
    if (t + 2 < NKT) { SA(d, 0); SB(d, 0); }
    G1_SYNC();
    G1_MFMA(1);
    __builtin_amdgcn_s_barrier();
    // phase 2
    G1_LDA(2);
    if (t + 2 < NKT) { SA(d, 1); SB(d, 1); }
    G1_SYNC();
    G1_MFMA(2);
    __builtin_amdgcn_s_barrier();
    // phase 3 (counted vmcnt: 6 loads of tile t+2 may stay in flight)
    G1_LDA(3);
    if (t + 2 < NKT) {
      SA(d, 2); SB(d, 2);
      asm volatile("s_waitcnt vmcnt(6)" ::: "memory");
    } else {
      asm volatile("s_waitcnt vmcnt(0)" ::: "memory");
    }
    G1_SYNC();
    G1_MFMA(3);
    __builtin_amdgcn_s_barrier();
  }

  // ---- epilogue: fold LoRA via one rank-8 (K=32 zero-padded) MFMA step
  __syncthreads();
  unsigned short* sLo2 = (unsigned short*)lds;            // [256][32] bf16: SCALE*low1
  unsigned short* sB2  = (unsigned short*)(lds + 16384);  // [256][32] bf16: Bgu rows (gate|up)
  {
    short8 z = {};
    if (tid < 256) {
      const float* lp = low + ((long)e * T_ + mt * 256 + tid) * R_;
      short8 v;
      #pragma unroll
      for (int r = 0; r < 8; ++r) ((unsigned short*)&v)[r] = f2bf(SCALE_ * lp[r]);
      *(short8*)(sLo2 + tid * 32) = v;
      *(short8*)(sLo2 + tid * 32 + 8) = z;
      *(short8*)(sLo2 + tid * 32 + 16) = z;
      *(short8*)(sLo2 + tid * 32 + 24) = z;
    } else {
      int r = tid - 256;
      long wrow = (r < 128) ? ((long)e * TWO_D_ + nt * 128 + r)
                            : ((long)e * TWO_D_ + D_ + nt * 128 + (r - 128));
      const float* bp = Bgu + wrow * R_;
      short8 v;
      #pragma unroll
      for (int k = 0; k < 8; ++k) ((unsigned short*)&v)[k] = f2bf(bp[k]);
      *(short8*)(sB2 + r * 32) = v;
      *(short8*)(sB2 + r * 32 + 8) = z;
      *(short8*)(sB2 + r * 32 + 16) = z;
      *(short8*)(sB2 + r * 32 + 24) = z;
    }
  }
  __syncthreads();
  {
    #pragma unroll
    for (int mi = 0; mi < 8; ++mi) {
      short8 alo = *(const short8*)(sLo2 + (rbA + mi * 16) * 32 + lq * 8);
      #pragma unroll
      for (int nj = 0; nj < 2; ++nj) {
        int rg = wn * 32 + nj * 16 + lrow;
        short8 bg2 = *(const short8*)(sB2 + rg * 32 + lq * 8);
        short8 bu2 = *(const short8*)(sB2 + (rg + 128) * 32 + lq * 8);
        accg[nj][mi] = __builtin_amdgcn_mfma_f32_16x16x32_bf16(bg2, alo, accg[nj][mi], 0, 0, 0);
        accu[nj][mi] = __builtin_amdgcn_mfma_f32_16x16x32_bf16(bu2, alo, accu[nj][mi], 0, 0, 0);
      }
    }
  }
  // silu + pack -> sT [256][136], then coalesced store
  unsigned short* sT = (unsigned short*)(lds + 32768);
  #pragma unroll
  for (int mi = 0; mi < 8; ++mi) {
    int tl = rbA + mi * 16;
    #pragma unroll
    for (int nj = 0; nj < 2; ++nj) {
      int cb = wn * 32 + nj * 16 + lq * 4;
      ushort4 o;
      #pragma unroll
      for (int j = 0; j < 4; ++j) {
        float gate = accg[nj][mi][j];
        float up   = accu[nj][mi][j];
        float hh = up * (gate / (1.f + __expf(-gate)));
        (&o.x)[j] = f2bf(hh);
      }
      *(ushort4*)(sT + tl * 136 + cb) = o;
    }
  }
  __syncthreads();
  {
    long base = ((long)e * T_ + mt * 256) * D_ + nt * 128;
    int rr2 = tid >> 4, cc2 = (tid & 15) * 8;
    #pragma unroll
    for (int p = 0; p < 8; ++p) {
      int r = p * 32 + rr2;
      short8 v = *(const short8*)(sT + r * 136 + cc2);
      *(short8*)(Hout + base + (long)r * D_ + cc2) = v;
    }
  }
}

// ======================= GEMM2: 256x256, BK=64, 8-phase =======================
// out = h@Wd^T + SCALE*low2@Bd^T (fp32 out; LoRA folded as rank-8 MFMA step)
__global__ __launch_bounds__(512, 2) void k_gemm2_8p(
    const unsigned short* __restrict__ Hin, const unsigned short* __restrict__ Wdb,
    const float* __restrict__ Bd, const float* __restrict__ low,
    float* __restrict__ Out) {
  __shared__ __align__(16) char lds[131072];

  const int MT = T_ / 256, NT = H_ / 256;  // 8, 8
  int b = blockIdx.x;
  int cpx = (int)gridDim.x >> 3;
  int swz = (b & 7) * cpx + (b >> 3);
  int e  = swz / (MT * NT);
  int r0 = swz % (MT * NT);
  int nt = r0 / MT, mt = r0 % MT;

  int tid = threadIdx.x, lane = tid & 63;
  int wid = tid >> 6, wm = wid >> 2, wn = wid & 3;
  int lrow = lane & 15, lq = lane >> 4;
  int X4 = (lrow & 7) << 4;
  const int NKT = D_ / 64;  // 64

  unsigned ro = (unsigned)tid * 16;
  unsigned so = ro ^ (((ro >> 7) & 7u) << 4);
  int sh = (so >> 12) & 1, sr = (so >> 7) & 31, sc = (so & 127) >> 1;
  const unsigned short* pA[4]; const unsigned short* pB[4];
  #pragma unroll
  for (int q = 0; q < 4; ++q) {
    long arow = (long)e * T_ + mt * 256 + sh * 128 + q * 32 + sr;
    pA[q] = Hin + arow * D_ + sc;
    long wrow = (long)e * H_ + nt * 256 + sh * 128 + q * 32 + sr;
    pB[q] = Wdb + wrow * (long)D_ + sc;
  }
  auto SA = [&](int d, int q) { gl16(pA[q], lds + d * 32768 + q * 8192 + ro); pA[q] += 64; };
  auto SB = [&](int d, int q) { gl16(pB[q], lds + 65536 + d * 32768 + q * 8192 + ro); pB[q] += 64; };

  f32x4 acc[8][4] = {};  // [mi][ni]
  short8 BF[4][2], af[2][2];

  SA(0,0); SB(0,0); SA(0,1); SB(0,1); SA(0,2); SB(0,2); SA(0,3); SB(0,3);
  SA(1,0); SB(1,0); SA(1,1); SB(1,1); SA(1,2); SB(1,2);
  asm volatile("s_waitcnt vmcnt(6)" ::: "memory");
  __builtin_amdgcn_s_barrier();

  int rbA = wm * 128 + lrow;
  for (int t = 0; t < NKT; ++t) {
    int d = t & 1;
    const char* Ab = lds + d * 32768;
    const char* Bb = lds + 65536 + d * 32768;

#define G2_MFMA(q)                                                                   \
    __builtin_amdgcn_s_setprio(1);                                                   \
    _Pragma("unroll") for (int m2 = 0; m2 < 2; ++m2)                                 \
      _Pragma("unroll") for (int ks = 0; ks < 2; ++ks)                               \
        _Pragma("unroll") for (int ni = 0; ni < 4; ++ni)                             \
          acc[(q)*2+m2][ni] = __builtin_amdgcn_mfma_f32_16x16x32_bf16(               \
              af[m2][ks], BF[ni][ks], acc[(q)*2+m2][ni], 0, 0, 0);                   \
    __builtin_amdgcn_s_setprio(0);

#define G2_LDA(q)                                                                    \
    _Pragma("unroll") for (int m2 = 0; m2 < 2; ++m2)                                 \
      _Pragma("unroll") for (int ks = 0; ks < 2; ++ks)                               \
        af[m2][ks] = *(const short8*)(Ab + (lds_off(rbA + ((q)*2+m2)*16, ks, lq) ^ X4));

    // phase 0
    #pragma unroll
    for (int ni = 0; ni < 4; ++ni)
      #pragma unroll
      for (int ks = 0; ks < 2; ++ks)
        BF[ni][ks] = *(const short8*)(Bb + (lds_off(wn * 64 + ni * 16 + lrow, ks, lq) ^ X4));
    G2_LDA(0);
    if (t + 1 < NKT) { SA(d ^ 1, 3); SB(d ^ 1, 3); }
    __builtin_amdgcn_s_barrier();
    asm volatile("s_waitcnt lgkmcnt(0)" ::: "memory");
    __builtin_amdgcn_sched_barrier(0);
    G2_MFMA(0);
    __builtin_amdgcn_s_barrier();
    // phase 1
    G2_LDA(1);
    if (t + 2 < NKT) { SA(d, 0); SB(d, 0); }
    __builtin_amdgcn_s_barrier();
    asm volatile("s_waitcnt lgkmcnt(0)" ::: "memory");
    __builtin_amdgcn_sched_barrier(0);
    G2_MFMA(1);
    __builtin_amdgcn_s_barrier();
    // phase 2
    G2_LDA(2);
    if (t + 2 < NKT) { SA(d, 1); SB(d, 1); }
    __builtin_amdgcn_s_barrier();
    asm volatile("s_waitcnt lgkmcnt(0)" ::: "memory");
    __builtin_amdgcn_sched_barrier(0);
    G2_MFMA(2);
    __builtin_amdgcn_s_barrier();
    // phase 3
    G2_LDA(3);
    if (t + 2 < NKT) {
      SA(d, 2); SB(d, 2);
      asm volatile("s_waitcnt vmcnt(6)" ::: "memory");
    } else {
      asm volatile("s_waitcnt vmcnt(0)" ::: "memory");
    }
    __builtin_amdgcn_s_barrier();
    asm volatile("s_waitcnt lgkmcnt(0)" ::: "memory");
    __builtin_amdgcn_sched_barrier(0);
    G2_MFMA(3);
    __builtin_amdgcn_s_barrier();
  }

  // ---- epilogue: LoRA via rank-8 MFMA, direct (row-major) stores
  __syncthreads();
  unsigned short* sLo2 = (unsigned short*)lds;            // [256][32] SCALE*low2
  unsigned short* sB2  = (unsigned short*)(lds + 16384);  // [256][32] Bd rows
  {
    short8 z = {};
    if (tid < 256) {
      const float* lp = low + ((long)e * T_ + mt * 256 + tid) * R_;
      short8 v;
      #pragma unroll
      for (int r = 0; r < 8; ++r) ((unsigned short*)&v)[r] = f2bf(SCALE_ * lp[r]);
      *(short8*)(sLo2 + tid * 32) = v;
      *(short8*)(sLo2 + tid * 32 + 8) = z;
      *(short8*)(sLo2 + tid * 32 + 16) = z;
      *(short8*)(sLo2 + tid * 32 + 24) = z;
    } else {
      int r = tid - 256;
      const float* bp = Bd + ((long)e * H_ + nt * 256 + r) * R_;
      short8 v;
      #pragma unroll
      for (int k = 0; k < 8; ++k) ((unsigned short*)&v)[k] = f2bf(bp[k]);
      *(short8*)(sB2 + r * 32) = v;
      *(short8*)(sB2 + r * 32 + 8) = z;
      *(short8*)(sB2 + r * 32 + 16) = z;
      *(short8*)(sB2 + r * 32 + 24) = z;
    }
  }
  __syncthreads();
  #pragma unroll
  for (int mi = 0; mi < 8; ++mi) {
    short8 alo = *(const short8*)(sLo2 + (rbA + mi * 16) * 32 + lq * 8);
    #pragma unroll
    for (int ni = 0; ni < 4; ++ni) {
      short8 bd2 = *(const short8*)(sB2 + (wn * 64 + ni * 16 + lrow) * 32 + lq * 8);
      acc[mi][ni] = __builtin_amdgcn_mfma_f32_16x16x32_bf16(alo, bd2, acc[mi][ni], 0, 0, 0);
    }
  }
  {
    long rowbase = (long)e * T_ + mt * 256 + wm * 128;
    int colbase = nt * 256 + wn * 64;
    #pragma unroll
    for (int mi = 0; mi < 8; ++mi)
      #pragma unroll
      for (int j = 0; j < 4; ++j) {
        long row = rowbase + mi * 16 + lq * 4 + j;
        #pragma unroll
        for (int ni = 0; ni < 4; ++ni)
          Out[row * H_ + colbase + ni * 16 + lrow] = acc[mi][ni][j];
      }
  }
}

extern "C" void kernel_launch(void* const* d_in, const int* in_sizes, int n_in,
                              void* d_out, int out_size, void* d_ws, size_t ws_size,
                              hipStream_t stream) {
  const float* x   = (const float*)d_in[0];
  const float* Wgu = (const float*)d_in[1];
  const float* Agu = (const float*)d_in[2];
  const float* Bgu = (const float*)d_in[3];
  const float* Wd  = (const float*)d_in[4];
  const float* Ad  = (const float*)d_in[5];
  const float* Bd  = (const float*)d_in[6];
  float* out = (float*)d_out;

  char* ws = (char*)d_ws;
  const size_t SZ_H   = (size_t)E_ * T_ * D_ * 2;        // 128 MiB bf16 h
  const size_t SZ_LOW = (size_t)E_ * T_ * R_ * 4;        // 512 KiB
  const size_t SZ_XB  = (size_t)E_ * T_ * H_ * 2;        // 64 MiB
  const size_t SZ_WGU = (size_t)E_ * TWO_D_ * H_ * 2;    // 256 MiB

  unsigned short* hbuf = (unsigned short*)ws;
  float* low1 = (float*)(ws + SZ_H);
  float* low2 = (float*)(ws + SZ_H + SZ_LOW);
  unsigned short* xb   = (unsigned short*)(ws + SZ_H + 2 * SZ_LOW);
  unsigned short* wgub = (unsigned short*)(ws + SZ_H + 2 * SZ_LOW + SZ_XB);
  unsigned short* wdb  = (unsigned short*)(ws + SZ_H + 2 * SZ_LOW + SZ_XB + SZ_WGU);

  // low1 + x->bf16 (4096 blocks) || Wgu->bf16 (1024 blocks)
  hipLaunchKernelGGL(k_pre, dim3(E_ * T_ / 4 + 1024), dim3(256), 0, stream,
                     x, Agu, low1, xb, Wgu, wgub);
  hipLaunchKernelGGL(k_gemm1_8p, dim3(E_ * (T_ / 256) * (D_ / 128)), dim3(512), 0, stream,
                     xb, wgub, Bgu, low1, hbuf);
  // low2 (4096 blocks) || Wd->bf16 (1024 blocks) — Wd conversion overlapped here, off the
  // serial-prefix critical path (gemm1 doesn't need wdb)
  hipLaunchKernelGGL(k_low2, dim3(E_ * T_ / 4 + 1024), dim3(256), 0, stream,
                     hbuf, Ad, low2, Wd, wdb);
  hipLaunchKernelGGL(k_gemm2_8p, dim3(E_ * (T_ / 256) * (H_ / 256)), dim3(512), 0, stream,
                     hbuf, wdb, Bd, low2, out);
}

// Round 13
// 1002.399 us; speedup vs baseline: 3.2408x; 1.1158x over previous
//
#include <hip/hip_runtime.h>
#include <hip/hip_bf16.h>

#define E_ 8
#define H_ 2048
#define D_ 4096
#define R_ 8
#define T_ 2048
#define TWO_D_ 8192
#define SCALE_ 2.0f

typedef __attribute__((ext_vector_type(8))) short short8;
typedef __attribute__((ext_vector_type(4))) float f32x4;

__device__ __forceinline__ unsigned short f2bf(float f) {
  union { float f; unsigned u; } c; c.f = f;
  unsigned u = c.u + 0x7fffu + ((c.u >> 16) & 1u);  // RNE
  return (unsigned short)(u >> 16);
}

// async 16B global -> LDS (linear dest: wave-uniform base + lane*16)
__device__ __forceinline__ void gl16(const void* g, void* l) {
  __builtin_amdgcn_global_load_lds(
      (const __attribute__((address_space(1))) void*)g,
      (__attribute__((address_space(3))) void*)l, 16, 0, 0);
}

// LDS byte offset inside a 32KB operand region laid out [qtr][half][32 rows][64 cols bf16]
__device__ __forceinline__ int lds_off(int rr, int ks, int lq) {
  return (((rr >> 5) & 3) << 13) | (((rr >> 7) & 1) << 12) | ((rr & 31) << 7) | (ks << 6) | (lq << 4);
}

// ---------------- pre-pass: x->bf16 || wgub = bf16(Wgu + SCALE*Bgu@Agu) || wdb = bf16(Wd + SCALE*Bd@Ad)
// LoRA folded into the weights (linearity) -> low1/low2 and GEMM epilogue folds all disappear.
__global__ __launch_bounds__(256) void k_pre(const float* __restrict__ x,
                                             unsigned short* __restrict__ xb,
                                             const float* __restrict__ Wgu,
                                             const float* __restrict__ Agu,
                                             const float* __restrict__ Bgu,
                                             unsigned short* __restrict__ wgub,
                                             const float* __restrict__ Wd,
                                             const float* __restrict__ Ad,
                                             const float* __restrict__ Bd,
                                             unsigned short* __restrict__ wdb) {
  const int NB_X = 1024, NB_GU = 8192;  // + 4096 for Wd
  int bb = blockIdx.x, tid = threadIdx.x;
  if (bb < NB_X) {
    // x -> bf16, grid-stride
    const long n = (long)E_ * T_ * H_;
    long i = ((long)bb * 256 + tid) * 8;
    const long stride = (long)NB_X * 256 * 8;
    for (; i < n; i += stride) {
      f32x4 a = *(const f32x4*)(x + i);
      f32x4 b = *(const f32x4*)(x + i + 4);
      ushort4 lo, hi;
      lo.x=f2bf(a[0]); lo.y=f2bf(a[1]); lo.z=f2bf(a[2]); lo.w=f2bf(a[3]);
      hi.x=f2bf(b[0]); hi.y=f2bf(b[1]); hi.z=f2bf(b[2]); hi.w=f2bf(b[3]);
      *(ushort4*)(xb + i) = lo;
      *(ushort4*)(xb + i + 4) = hi;
    }
  } else if (bb < NB_X + NB_GU) {
    // Wgu fold: block covers 8 consecutive output rows of one expert; thread covers 8 cols.
    int b2 = bb - NB_X;
    int e = b2 >> 10;                    // / 1024
    int o8 = (b2 & 1023) * 8;
    int c = tid * 8;
    f32x4 a0[8], a1[8];
    #pragma unroll
    for (int r = 0; r < 8; ++r) {
      const float* ap = Agu + ((long)e * R_ + r) * H_ + c;
      a0[r] = *(const f32x4*)ap;
      a1[r] = *(const f32x4*)(ap + 4);
    }
    #pragma unroll
    for (int o = 0; o < 8; ++o) {
      long row = (long)e * TWO_D_ + o8 + o;
      const float* bp = Bgu + row * R_;
      const float* wp = Wgu + row * (long)H_ + c;
      f32x4 w0 = *(const f32x4*)wp;
      f32x4 w1 = *(const f32x4*)(wp + 4);
      #pragma unroll
      for (int r = 0; r < 8; ++r) {
        float s = SCALE_ * bp[r];
        w0 += s * a0[r];
        w1 += s * a1[r];
      }
      ushort4 lo, hi;
      lo.x=f2bf(w0[0]); lo.y=f2bf(w0[1]); lo.z=f2bf(w0[2]); lo.w=f2bf(w0[3]);
      hi.x=f2bf(w1[0]); hi.y=f2bf(w1[1]); hi.z=f2bf(w1[2]); hi.w=f2bf(w1[3]);
      unsigned short* op = wgub + row * (long)H_ + c;
      *(ushort4*)op = lo;
      *(ushort4*)(op + 4) = hi;
    }
  } else {
    // Wd fold: block covers 8 consecutive h-rows x one half of D; thread covers 8 cols.
    int b2 = bb - NB_X - NB_GU;
    int e = b2 >> 9;                     // / 512
    int rem = b2 & 511;
    int h8 = (rem >> 1) * 8;
    int c = (rem & 1) * 2048 + tid * 8;
    f32x4 a0[8], a1[8];
    #pragma unroll
    for (int r = 0; r < 8; ++r) {
      const float* ap = Ad + ((long)e * R_ + r) * D_ + c;
      a0[r] = *(const f32x4*)ap;
      a1[r] = *(const f32x4*)(ap + 4);
    }
    #pragma unroll
    for (int o = 0; o < 8; ++o) {
      long row = (long)e * H_ + h8 + o;
      const float* bp = Bd + row * R_;
      const float* wp = Wd + row * (long)D_ + c;
      f32x4 w0 = *(const f32x4*)wp;
      f32x4 w1 = *(const f32x4*)(wp + 4);
      #pragma unroll
      for (int r = 0; r < 8; ++r) {
        float s = SCALE_ * bp[r];
        w0 += s * a0[r];
        w1 += s * a1[r];
      }
      ushort4 lo, hi;
      lo.x=f2bf(w0[0]); lo.y=f2bf(w0[1]); lo.z=f2bf(w0[2]); lo.w=f2bf(w0[3]);
      hi.x=f2bf(w1[0]); hi.y=f2bf(w1[1]); hi.z=f2bf(w1[2]); hi.w=f2bf(w1[3]);
      unsigned short* op = wdb + row * (long)D_ + c;
      *(ushort4*)op = lo;
      *(ushort4*)(op + 4) = hi;
    }
  }
}

// ======================= GEMM1: 256x128(gate)+128(up), BK=64, 8-phase =======================
// h = up*silu(gate); gate_up = x@Wgu'^T (LoRA pre-folded into weights)
__global__ __launch_bounds__(512, 2) void k_gemm1_8p(
    const unsigned short* __restrict__ Xb, const unsigned short* __restrict__ Wb,
    unsigned short* __restrict__ Hout) {
  __shared__ __align__(16) char lds[131072];  // A: d*32768, B: 65536 + d*32768

  const int MT = T_ / 256, NT = D_ / 128;  // 8, 32
  int b = blockIdx.x;
  int cpx = (int)gridDim.x >> 3;
  int swz = (b & 7) * cpx + (b >> 3);     // bijective: grid % 8 == 0
  int e  = swz / (MT * NT);
  int r0 = swz % (MT * NT);
  int nt = r0 / MT, mt = r0 % MT;

  int tid = threadIdx.x, lane = tid & 63;
  int wid = tid >> 6, wm = wid >> 2, wn = wid & 3;
  int lrow = lane & 15, lq = lane >> 4;
  int X4 = (lrow & 7) << 4;
  const int NKT = H_ / 64;  // 32

  unsigned ro = (unsigned)tid * 16;
  unsigned so = ro ^ (((ro >> 7) & 7u) << 4);
  int sh = (so >> 12) & 1, sr = (so >> 7) & 31, sc = (so & 127) >> 1;
  const unsigned short* pA[4]; const unsigned short* pB[4];
  #pragma unroll
  for (int q = 0; q < 4; ++q) {
    long arow = (long)e * T_ + mt * 256 + sh * 128 + q * 32 + sr;
    pA[q] = Xb + arow * H_ + sc;
    long wrow = sh ? ((long)e * TWO_D_ + D_ + nt * 128 + q * 32 + sr)
                   : ((long)e * TWO_D_ +      nt * 128 + q * 32 + sr);
    pB[q] = Wb + wrow * (long)H_ + sc;
  }
  auto SA = [&](int d, int q) { gl16(pA[q], lds + d * 32768 + q * 8192 + ro); pA[q] += 64; };
  auto SB = [&](int d, int q) { gl16(pB[q], lds + 65536 + d * 32768 + q * 8192 + ro); pB[q] += 64; };

  f32x4 accg[2][8] = {}, accu[2][8] = {};  // [nj][mi]
  short8 BG[2][2], BU[2][2], af[2][2];

  SA(0,0); SB(0,0); SA(0,1); SB(0,1); SA(0,2); SB(0,2); SA(0,3); SB(0,3);
  SA(1,0); SB(1,0); SA(1,1); SB(1,1); SA(1,2); SB(1,2);
  asm volatile("s_waitcnt vmcnt(6)" ::: "memory");
  __builtin_amdgcn_s_barrier();

  int rbA = wm * 128 + lrow;
  for (int t = 0; t < NKT; ++t) {
    int d = t & 1;
    const char* Ab = lds + d * 32768;
    const char* Bb = lds + 65536 + d * 32768;

#define G1_MFMA(q)                                                                   \
    __builtin_amdgcn_s_setprio(1);                                                   \
    _Pragma("unroll") for (int m2 = 0; m2 < 2; ++m2)                                 \
      _Pragma("unroll") for (int ks = 0; ks < 2; ++ks)                               \
        _Pragma("unroll") for (int nj = 0; nj < 2; ++nj) {                           \
          accg[nj][(q)*2+m2] = __builtin_amdgcn_mfma_f32_16x16x32_bf16(              \
              BG[nj][ks], af[m2][ks], accg[nj][(q)*2+m2], 0, 0, 0);                  \
          accu[nj][(q)*2+m2] = __builtin_amdgcn_mfma_f32_16x16x32_bf16(              \
              BU[nj][ks], af[m2][ks], accu[nj][(q)*2+m2], 0, 0, 0);                  \
        }                                                                            \
    __builtin_amdgcn_s_setprio(0);

#define G1_LDA(q)                                                                    \
    _Pragma("unroll") for (int m2 = 0; m2 < 2; ++m2)                                 \
      _Pragma("unroll") for (int ks = 0; ks < 2; ++ks)                               \
        af[m2][ks] = *(const short8*)(Ab + (lds_off(rbA + ((q)*2+m2)*16, ks, lq) ^ X4));

#define G1_SYNC()                                                                    \
    __builtin_amdgcn_s_barrier();                                                    \
    asm volatile("s_waitcnt lgkmcnt(0)" ::: "memory");                               \
    __builtin_amdgcn_sched_barrier(0);

    // phase 0: B-frags + A-quad0; stage tile t+1 last units
    #pragma unroll
    for (int nj = 0; nj < 2; ++nj)
      #pragma unroll
      for (int ks = 0; ks < 2; ++ks) {
        int rg = wn * 32 + nj * 16 + lrow;
        BG[nj][ks] = *(const short8*)(Bb + (lds_off(rg, ks, lq) ^ X4));
        BU[nj][ks] = *(const short8*)(Bb + (lds_off(rg + 128, ks, lq) ^ X4));
      }
    G1_LDA(0);
    if (t + 1 < NKT) { SA(d ^ 1, 3); SB(d ^ 1, 3); }
    G1_SYNC();
    G1_MFMA(0);
    __builtin_amdgcn_s_barrier();
    // phase 1
    G1_LDA(1);
    if (t + 2 < NKT) { SA(d, 0); SB(d, 0); }
    G1_SYNC();
    G1_MFMA(1);
    __builtin_amdgcn_s_barrier();
    // phase 2
    G1_LDA(2);
    if (t + 2 < NKT) { SA(d, 1); SB(d, 1); }
    G1_SYNC();
    G1_MFMA(2);
    __builtin_amdgcn_s_barrier();
    // phase 3 (counted vmcnt: 6 loads of tile t+2 may stay in flight)
    G1_LDA(3);
    if (t + 2 < NKT) {
      SA(d, 2); SB(d, 2);
      asm volatile("s_waitcnt vmcnt(6)" ::: "memory");
    } else {
      asm volatile("s_waitcnt vmcnt(0)" ::: "memory");
    }
    G1_SYNC();
    G1_MFMA(3);
    __builtin_amdgcn_s_barrier();
  }

  // ---- epilogue: silu + pack -> sT [256][136], then coalesced store
  __syncthreads();
  unsigned short* sT = (unsigned short*)(lds + 32768);
  #pragma unroll
  for (int mi = 0; mi < 8; ++mi) {
    int tl = rbA + mi * 16;
    #pragma unroll
    for (int nj = 0; nj < 2; ++nj) {
      int cb = wn * 32 + nj * 16 + lq * 4;
      ushort4 o;
      #pragma unroll
      for (int j = 0; j < 4; ++j) {
        float gate = accg[nj][mi][j];
        float up   = accu[nj][mi][j];
        float hh = up * (gate / (1.f + __expf(-gate)));
        (&o.x)[j] = f2bf(hh);
      }
      *(ushort4*)(sT + tl * 136 + cb) = o;
    }
  }
  __syncthreads();
  {
    long base = ((long)e * T_ + mt * 256) * D_ + nt * 128;
    int rr2 = tid >> 4, cc2 = (tid & 15) * 8;
    #pragma unroll
    for (int p = 0; p < 8; ++p) {
      int r = p * 32 + rr2;
      short8 v = *(const short8*)(sT + r * 136 + cc2);
      *(short8*)(Hout + base + (long)r * D_ + cc2) = v;
    }
  }
}

// ======================= GEMM2: 256x256, BK=64, 8-phase =======================
// out = h@Wd'^T (fp32 out; LoRA pre-folded into weights)
__global__ __launch_bounds__(512, 2) void k_gemm2_8p(
    const unsigned short* __restrict__ Hin, const unsigned short* __restrict__ Wdb,
    float* __restrict__ Out) {
  __shared__ __align__(16) char lds[131072];

  const int MT = T_ / 256, NT = H_ / 256;  // 8, 8
  int b = blockIdx.x;
  int cpx = (int)gridDim.x >> 3;
  int swz = (b & 7) * cpx + (b >> 3);
  int e  = swz / (MT * NT);
  int r0 = swz % (MT * NT);
  int nt = r0 / MT, mt = r0 % MT;

  int tid = threadIdx.x, lane = tid & 63;
  int wid = tid >> 6, wm = wid >> 2, wn = wid & 3;
  int lrow = lane & 15, lq = lane >> 4;
  int X4 = (lrow & 7) << 4;
  const int NKT = D_ / 64;  // 64

  unsigned ro = (unsigned)tid * 16;
  unsigned so = ro ^ (((ro >> 7) & 7u) << 4);
  int sh = (so >> 12) & 1, sr = (so >> 7) & 31, sc = (so & 127) >> 1;
  const unsigned short* pA[4]; const unsigned short* pB[4];
  #pragma unroll
  for (int q = 0; q < 4; ++q) {
    long arow = (long)e * T_ + mt * 256 + sh * 128 + q * 32 + sr;
    pA[q] = Hin + arow * D_ + sc;
    long wrow = (long)e * H_ + nt * 256 + sh * 128 + q * 32 + sr;
    pB[q] = Wdb + wrow * (long)D_ + sc;
  }
  auto SA = [&](int d, int q) { gl16(pA[q], lds + d * 32768 + q * 8192 + ro); pA[q] += 64; };
  auto SB = [&](int d, int q) { gl16(pB[q], lds + 65536 + d * 32768 + q * 8192 + ro); pB[q] += 64; };

  f32x4 acc[8][4] = {};  // [mi][ni]
  short8 BF[4][2], af[2][2];

  SA(0,0); SB(0,0); SA(0,1); SB(0,1); SA(0,2); SB(0,2); SA(0,3); SB(0,3);
  SA(1,0); SB(1,0); SA(1,1); SB(1,1); SA(1,2); SB(1,2);
  asm volatile("s_waitcnt vmcnt(6)" ::: "memory");
  __builtin_amdgcn_s_barrier();

  int rbA = wm * 128 + lrow;
  for (int t = 0; t < NKT; ++t) {
    int d = t & 1;
    const char* Ab = lds + d * 32768;
    const char* Bb = lds + 65536 + d * 32768;

#define G2_MFMA(q)                                                                   \
    __builtin_amdgcn_s_setprio(1);                                                   \
    _Pragma("unroll") for (int m2 = 0; m2 < 2; ++m2)                                 \
      _Pragma("unroll") for (int ks = 0; ks < 2; ++ks)                               \
        _Pragma("unroll") for (int ni = 0; ni < 4; ++ni)                             \
          acc[(q)*2+m2][ni] = __builtin_amdgcn_mfma_f32_16x16x32_bf16(               \
              af[m2][ks], BF[ni][ks], acc[(q)*2+m2][ni], 0, 0, 0);                   \
    __builtin_amdgcn_s_setprio(0);

#define G2_LDA(q)                                                                    \
    _Pragma("unroll") for (int m2 = 0; m2 < 2; ++m2)                                 \
      _Pragma("unroll") for (int ks = 0; ks < 2; ++ks)                               \
        af[m2][ks] = *(const short8*)(Ab + (lds_off(rbA + ((q)*2+m2)*16, ks, lq) ^ X4));

    // phase 0
    #pragma unroll
    for (int ni = 0; ni < 4; ++ni)
      #pragma unroll
      for (int ks = 0; ks < 2; ++ks)
        BF[ni][ks] = *(const short8*)(Bb + (lds_off(wn * 64 + ni * 16 + lrow, ks, lq) ^ X4));
    G2_LDA(0);
    if (t + 1 < NKT) { SA(d ^ 1, 3); SB(d ^ 1, 3); }
    __builtin_amdgcn_s_barrier();
    asm volatile("s_waitcnt lgkmcnt(0)" ::: "memory");
    __builtin_amdgcn_sched_barrier(0);
    G2_MFMA(0);
    __builtin_amdgcn_s_barrier();
    // phase 1
    G2_LDA(1);
    if (t + 2 < NKT) { SA(d, 0); SB(d, 0); }
    __builtin_amdgcn_s_barrier();
    asm volatile("s_waitcnt lgkmcnt(0)" ::: "memory");
    __builtin_amdgcn_sched_barrier(0);
    G2_MFMA(1);
    __builtin_amdgcn_s_barrier();
    // phase 2
    G2_LDA(2);
    if (t + 2 < NKT) { SA(d, 1); SB(d, 1); }
    __builtin_amdgcn_s_barrier();
    asm volatile("s_waitcnt lgkmcnt(0)" ::: "memory");
    __builtin_amdgcn_sched_barrier(0);
    G2_MFMA(2);
    __builtin_amdgcn_s_barrier();
    // phase 3
    G2_LDA(3);
    if (t + 2 < NKT) {
      SA(d, 2); SB(d, 2);
      asm volatile("s_waitcnt vmcnt(6)" ::: "memory");
    } else {
      asm volatile("s_waitcnt vmcnt(0)" ::: "memory");
    }
    __builtin_amdgcn_s_barrier();
    asm volatile("s_waitcnt lgkmcnt(0)" ::: "memory");
    __builtin_amdgcn_sched_barrier(0);
    G2_MFMA(3);
    __builtin_amdgcn_s_barrier();
  }

  // ---- epilogue: direct (row-major) stores
  {
    long rowbase = (long)e * T_ + mt * 256 + wm * 128;
    int colbase = nt * 256 + wn * 64;
    #pragma unroll
    for (int mi = 0; mi < 8; ++mi)
      #pragma unroll
      for (int j = 0; j < 4; ++j) {
        long row = rowbase + mi * 16 + lq * 4 + j;
        #pragma unroll
        for (int ni = 0; ni < 4; ++ni)
          Out[row * H_ + colbase + ni * 16 + lrow] = acc[mi][ni][j];
      }
  }
}

extern "C" void kernel_launch(void* const* d_in, const int* in_sizes, int n_in,
                              void* d_out, int out_size, void* d_ws, size_t ws_size,
                              hipStream_t stream) {
  const float* x   = (const float*)d_in[0];
  const float* Wgu = (const float*)d_in[1];
  const float* Agu = (const float*)d_in[2];
  const float* Bgu = (const float*)d_in[3];
  const float* Wd  = (const float*)d_in[4];
  const float* Ad  = (const float*)d_in[5];
  const float* Bd  = (const float*)d_in[6];
  float* out = (float*)d_out;

  char* ws = (char*)d_ws;
  const size_t SZ_H   = (size_t)E_ * T_ * D_ * 2;        // 128 MiB bf16 h
  const size_t SZ_LOW = (size_t)E_ * T_ * R_ * 4;        // kept for layout stability
  const size_t SZ_XB  = (size_t)E_ * T_ * H_ * 2;        // 64 MiB
  const size_t SZ_WGU = (size_t)E_ * TWO_D_ * H_ * 2;    // 256 MiB

  unsigned short* hbuf = (unsigned short*)ws;
  unsigned short* xb   = (unsigned short*)(ws + SZ_H + 2 * SZ_LOW);
  unsigned short* wgub = (unsigned short*)(ws + SZ_H + 2 * SZ_LOW + SZ_XB);
  unsigned short* wdb  = (unsigned short*)(ws + SZ_H + 2 * SZ_LOW + SZ_XB + SZ_WGU);

  // x->bf16 (1024 blocks) || Wgu-fold->bf16 (8192 blocks) || Wd-fold->bf16 (4096 blocks)
  hipLaunchKernelGGL(k_pre, dim3(1024 + 8192 + 4096), dim3(256), 0, stream,
                     x, xb, Wgu, Agu, Bgu, wgub, Wd, Ad, Bd, wdb);
  hipLaunchKernelGGL(k_gemm1_8p, dim3(E_ * (T_ / 256) * (D_ / 128)), dim3(512), 0, stream,
                     xb, wgub, hbuf);
  hipLaunchKernelGGL(k_gemm2_8p, dim3(E_ * (T_ / 256) * (H_ / 256)), dim3(512), 0, stream,
                     hbuf, wdb, out);
}